// Round 4
// baseline (208.990 us; speedup 1.0000x reference)
//
#include <hip/hip_runtime.h>
#include <math.h>

// B=1, I=J=256, C=128, H=4, CH=32
#define NI 256
#define NJ 256
#define NC 128
#define NH 4
#define NCH 32

typedef __attribute__((ext_vector_type(8)))  __bf16        bf16x8;
typedef __attribute__((ext_vector_type(8)))  unsigned short u16x8;
typedef __attribute__((ext_vector_type(4)))  unsigned int   u32x4;
typedef __attribute__((ext_vector_type(16))) float         f32x16;

__device__ __forceinline__ unsigned short f2bf(float f) {
    unsigned u = __builtin_bit_cast(unsigned, f);
    u += 0x7fffu + ((u >> 16) & 1u);          // RNE
    return (unsigned short)(u >> 16);
}
__device__ __forceinline__ float bf2f(unsigned short s) {
    return __builtin_bit_cast(float, ((unsigned)s) << 16);
}
__device__ __forceinline__ f32x16 fzero16() {
    f32x16 z;
#pragma unroll
    for (int r = 0; r < 16; ++r) z[r] = 0.f;
    return z;
}
__device__ __forceinline__ f32x16 mfma16(bf16x8 a, bf16x8 b, f32x16 c) {
    return __builtin_amdgcn_mfma_f32_32x32x16_bf16(a, b, c, 0, 0, 0);
}

// ---------------------------------------------------------------------------
// Kernel 0: transpose+convert weights to bf16.
// ---------------------------------------------------------------------------
__global__ __launch_bounds__(256) void convert_weights(
    const float* __restrict__ wq, const float* __restrict__ wk,
    const float* __restrict__ wv, const float* __restrict__ wg,
    const float* __restrict__ wo, const float* __restrict__ w_tri,
    unsigned short* __restrict__ Wt_all, unsigned short* __restrict__ Wto,
    unsigned short* __restrict__ Wtri_pad)
{
    int id = blockIdx.x * 256 + threadIdx.x;          // 0..86015
    if (id < 4 * 16384) {
        int m = id >> 14, r = id & 16383;
        int kk = r >> 7, c = r & 127;
        const float* W = (m == 0) ? wq : (m == 1) ? wk : (m == 2) ? wv : wg;
        Wt_all[(m * 128 + c) * 128 + kk] = f2bf(W[kk * 128 + c]);
    } else if (id < 5 * 16384) {
        int r = id - 4 * 16384;
        int kk = r >> 7, c = r & 127;
        Wto[c * 128 + kk] = f2bf(wo[kk * 128 + c]);
    } else {
        int r = id - 5 * 16384;                        // 0..4095
        int col = r >> 7, kk = r & 127;
        Wtri_pad[col * 128 + kk] = (col < NH) ? f2bf(w_tri[kk * NH + col]) : (unsigned short)0;
    }
}

// ---------------------------------------------------------------------------
// Kernel 1: LayerNorm + MFMA projections (q,k,v,g) + tri bias via MFMA.
// ---------------------------------------------------------------------------
#define XNP 136
__global__ __launch_bounds__(256, 2) void ln_proj_mfma(
    const float* __restrict__ x, const float* __restrict__ ln_w, const float* __restrict__ ln_b,
    const unsigned short* __restrict__ Wt_all, const unsigned short* __restrict__ Wtri_pad,
    const float* __restrict__ bg,
    unsigned short* __restrict__ q, unsigned short* __restrict__ k,
    unsigned short* __restrict__ v, unsigned short* __restrict__ g,
    float* __restrict__ tri)
{
    __shared__ unsigned short xn[64 * XNP];   // ~17.4 KB
    const int tid = threadIdx.x;
    const long tok0 = (long)blockIdx.x * 64;

    const int lane8 = tid & 7;
#pragma unroll
    for (int p = 0; p < 2; ++p) {
        const int t = p * 32 + (tid >> 3);
        const float4* xrow = (const float4*)(x + (tok0 + t) * NC + lane8 * 16);
        float4 xv[4];
        float s = 0.f;
#pragma unroll
        for (int u = 0; u < 4; ++u) {
            xv[u] = xrow[u];
            s += xv[u].x + xv[u].y + xv[u].z + xv[u].w;
        }
#pragma unroll
        for (int off = 4; off; off >>= 1) s += __shfl_down(s, off, 8);
        const float mu = __shfl(s, 0, 8) * (1.f / (float)NC);
        float s2 = 0.f;
#pragma unroll
        for (int u = 0; u < 4; ++u) {
            float dx;
            dx = xv[u].x - mu; s2 += dx * dx;
            dx = xv[u].y - mu; s2 += dx * dx;
            dx = xv[u].z - mu; s2 += dx * dx;
            dx = xv[u].w - mu; s2 += dx * dx;
        }
#pragma unroll
        for (int off = 4; off; off >>= 1) s2 += __shfl_down(s2, off, 8);
        const float rstd = rsqrtf(__shfl(s2, 0, 8) * (1.f / (float)NC) + 1e-5f);
#pragma unroll
        for (int u = 0; u < 4; ++u) {
            const int c = lane8 * 16 + u * 4;
            const float4 lw = *(const float4*)(ln_w + c);
            const float4 lb = *(const float4*)(ln_b + c);
            float o0 = (xv[u].x - mu) * rstd * lw.x + lb.x;
            float o1 = (xv[u].y - mu) * rstd * lw.y + lb.y;
            float o2 = (xv[u].z - mu) * rstd * lw.z + lb.z;
            float o3 = (xv[u].w - mu) * rstd * lw.w + lb.w;
            unsigned p0 = (unsigned)f2bf(o0) | ((unsigned)f2bf(o1) << 16);
            unsigned p1 = (unsigned)f2bf(o2) | ((unsigned)f2bf(o3) << 16);
            *(unsigned*)&xn[t * XNP + c]     = p0;
            *(unsigned*)&xn[t * XNP + c + 2] = p1;
        }
    }
    __syncthreads();

    const int w = tid >> 6, L = tid & 63, lh = L >> 5, lc = L & 31;
    f32x16 acc[2][4], accT[2];
#pragma unroll
    for (int mt = 0; mt < 2; ++mt) {
        accT[mt] = fzero16();
#pragma unroll
        for (int nt = 0; nt < 4; ++nt) acc[mt][nt] = fzero16();
    }

#pragma unroll
    for (int k0 = 0; k0 < 8; ++k0) {
        bf16x8 a0 = *(const bf16x8*)&xn[(lc)      * XNP + k0 * 16 + lh * 8];
        bf16x8 a1 = *(const bf16x8*)&xn[(32 + lc) * XNP + k0 * 16 + lh * 8];
#pragma unroll
        for (int nt = 0; nt < 4; ++nt) {
            const int ntile = w + 4 * nt;
            bf16x8 b = *(const bf16x8*)&Wt_all[(ntile * 32 + lc) * 128 + k0 * 16 + lh * 8];
            acc[0][nt] = mfma16(a0, b, acc[0][nt]);
            acc[1][nt] = mfma16(a1, b, acc[1][nt]);
        }
        bf16x8 bt = *(const bf16x8*)&Wtri_pad[lc * 128 + k0 * 16 + lh * 8];
        accT[0] = mfma16(a0, bt, accT[0]);
        accT[1] = mfma16(a1, bt, accT[1]);
    }

    const int a_row = (int)(tok0 >> 8);
    const int b0    = (int)(tok0 & 255);
    int rowl[16];
#pragma unroll
    for (int r = 0; r < 16; ++r) rowl[r] = (r & 3) + 8 * (r >> 2) + 4 * lh;

    const float bgv = bg[w * 32 + lc];
#pragma unroll
    for (int nt = 0; nt < 4; ++nt) {
        unsigned short* O = (nt == 0) ? q : (nt == 1) ? k : (nt == 2) ? v : g;
        unsigned short* Ob = O + (((long)a_row * NH + w) * NJ + b0) * NCH + lc;
#pragma unroll
        for (int mt = 0; mt < 2; ++mt) {
#pragma unroll
            for (int r = 0; r < 16; ++r) {
                const int row = mt * 32 + rowl[r];
                float val = acc[mt][nt][r];
                if (nt == 0) val *= 0.17677669529663689f;        // CH^-0.5
                if (nt == 3) val = __builtin_amdgcn_rcpf(1.f + __expf(-(val + bgv)));
                Ob[(long)row * NCH] = f2bf(val);
            }
        }
    }
    if (lc < NH) {
        float* tb = tri + ((long)lc * NI + a_row) * NJ + b0;
#pragma unroll
        for (int mt = 0; mt < 2; ++mt)
#pragma unroll
            for (int r = 0; r < 16; ++r)
                tb[mt * 32 + rowl[r]] = accT[mt][r];
    }
}

// ---------------------------------------------------------------------------
// Kernel 2: MFMA attention, S^T formulation.
//   S^T = mfma(K_frag, Q_frag): lane holds q=lc (fixed), key=reg pattern.
//   Softmax sum: per-lane scalar + one shfl_xor(32).
//   P^T B-frag built in-register (2 shfl_xor + selects per K=16 step).
//   O^T = mfma(Vt_frag, Pt_frag): lane holds q=lc, ch=reg pattern.
// ---------------------------------------------------------------------------
#define KSP 40
#define VTP 264
__global__ __launch_bounds__(256, 3) void attn_mfma(
    const unsigned short* __restrict__ q, const unsigned short* __restrict__ k,
    const unsigned short* __restrict__ v, const unsigned short* __restrict__ g,
    const float* __restrict__ tri, const float* __restrict__ mask,
    unsigned short* __restrict__ og)
{
    __shared__ unsigned short Ks[256 * KSP];      // 20 KB
    __shared__ unsigned short Vt[32 * VTP];       // 16.5 KB
    __shared__ float maskb[256];                  // 1 KB
    const int i = blockIdx.x, h = blockIdx.y, qh = blockIdx.z;
    const int tid = threadIdx.x;
    const int w = tid >> 6, L = tid & 63, lh = L >> 5, lc = L & 31;
    const long base = ((long)i * NH + h) * NJ * NCH;

#pragma unroll
    for (int it = 0; it < 4; ++it) {
        const int idx = it * 256 + tid;
        const int key = idx >> 2, c8 = (idx & 3) * 8;
        *(bf16x8*)&Ks[key * KSP + c8] = *(const bf16x8*)(k + base + key * NCH + c8);
    }
    {
        const int key = tid;
        const u16x8 r0 = *(const u16x8*)(v + base + key * NCH);
        const u16x8 r1 = *(const u16x8*)(v + base + key * NCH + 8);
        const u16x8 r2 = *(const u16x8*)(v + base + key * NCH + 16);
        const u16x8 r3 = *(const u16x8*)(v + base + key * NCH + 24);
#pragma unroll
        for (int u = 0; u < 8; ++u) {
            Vt[(u)      * VTP + key] = r0[u];
            Vt[(u + 8)  * VTP + key] = r1[u];
            Vt[(u + 16) * VTP + key] = r2[u];
            Vt[(u + 24) * VTP + key] = r3[u];
        }
    }
    maskb[tid] = 1.0e9f * (mask[i * NJ + tid] - 1.0f);
    __syncthreads();

    const int qt = qh * 4 + w;               // q-tile 0..7
    const int qbase = qt * 32;
    const int qrow  = qbase + lc;            // this lane's query

    // Q B-frag (B-frag of Q^T == A-frag of Q): unchanged pattern
    const bf16x8 a0 = *(const bf16x8*)(q + base + (long)qrow * NCH + lh * 8);
    const bf16x8 a1 = *(const bf16x8*)(q + base + (long)qrow * NCH + 16 + lh * 8);
    const float* trirow = tri + ((long)h * NI + qrow) * NJ;

    float ls = 0.f;
    f32x16 O = fzero16();

#pragma unroll
    for (int t = 0; t < 8; ++t) {
        // ---- S^T tile: keys t*32 + rowl(reg), q = lc ----
        bf16x8 kb0 = *(const bf16x8*)&Ks[(t * 32 + lc) * KSP + lh * 8];
        bf16x8 kb1 = *(const bf16x8*)&Ks[(t * 32 + lc) * KSP + 16 + lh * 8];
        f32x16 s = fzero16();
        s = mfma16(kb0, a0, s);
        s = mfma16(kb1, a1, s);

        // ---- bias + exp + per-lane sum; pack to bf16 pairs ----
        unsigned pk[8];
#pragma unroll
        for (int gg = 0; gg < 4; ++gg) {
            const int kb = t * 32 + gg * 8 + 4 * lh;
            const float4 tb = *(const float4*)(trirow + kb);
            const float4 mb = *(const float4*)&maskb[kb];
            const float p0 = __expf(fminf(s[4 * gg + 0] + tb.x + mb.x, 30.f));
            const float p1 = __expf(fminf(s[4 * gg + 1] + tb.y + mb.y, 30.f));
            const float p2 = __expf(fminf(s[4 * gg + 2] + tb.z + mb.z, 30.f));
            const float p3 = __expf(fminf(s[4 * gg + 3] + tb.w + mb.w, 30.f));
            ls += (p0 + p1) + (p2 + p3);
            pk[2 * gg]     = (unsigned)f2bf(p0) | ((unsigned)f2bf(p1) << 16);
            pk[2 * gg + 1] = (unsigned)f2bf(p2) | ((unsigned)f2bf(p3) << 16);
        }

        // ---- O^T += V^T @ P^T, two K=16 steps ----
#pragma unroll
        for (int ss = 0; ss < 2; ++ss) {
            // exchange with lane^32: each lane provides the pair its partner needs
            const unsigned give0 = lh ? pk[4 * ss]     : pk[4 * ss + 2];
            const unsigned give1 = lh ? pk[4 * ss + 1] : pk[4 * ss + 3];
            const unsigned t0 = __shfl_xor(give0, 32);
            const unsigned t1 = __shfl_xor(give1, 32);
            u32x4 bw;
            bw[0] = lh ? t0 : pk[4 * ss];
            bw[1] = lh ? t1 : pk[4 * ss + 1];
            bw[2] = lh ? pk[4 * ss + 2] : t0;
            bw[3] = lh ? pk[4 * ss + 3] : t1;
            const bf16x8 pb = __builtin_bit_cast(bf16x8, bw);
            const bf16x8 va = *(const bf16x8*)&Vt[lc * VTP + t * 32 + ss * 16 + lh * 8];
            O = mfma16(va, pb, O);
        }
    }

    // ---- epilogue: per-lane normalize, gate, 8B vector stores ----
    ls += __shfl_xor(ls, 32);
    const float rl = __builtin_amdgcn_rcpf(ls);
    const unsigned short* gb = g + base + (long)qrow * NCH;
    unsigned short* ob = og + ((long)i * NJ + qrow) * NC + h * NCH;
#pragma unroll
    for (int gg = 0; gg < 4; ++gg) {
        const int ch = gg * 8 + 4 * lh;
        const ushort4 gv = *(const ushort4*)(gb + ch);
        const float v0 = O[4 * gg + 0] * rl * bf2f(gv.x);
        const float v1 = O[4 * gg + 1] * rl * bf2f(gv.y);
        const float v2 = O[4 * gg + 2] * rl * bf2f(gv.z);
        const float v3 = O[4 * gg + 3] * rl * bf2f(gv.w);
        uint2 st;
        st.x = (unsigned)f2bf(v0) | ((unsigned)f2bf(v1) << 16);
        st.y = (unsigned)f2bf(v2) | ((unsigned)f2bf(v3) << 16);
        *(uint2*)(ob + ch) = st;
    }
}

// ---------------------------------------------------------------------------
// Kernel 3: out = og @ wo + bo  (MFMA).
// ---------------------------------------------------------------------------
#define OGP 136
__global__ __launch_bounds__(256, 4) void out_proj_mfma(
    const unsigned short* __restrict__ og, const unsigned short* __restrict__ Wto,
    const float* __restrict__ bo, float* __restrict__ out)
{
    __shared__ unsigned short t_og[64 * OGP];
    const int tid = threadIdx.x;
    const long tok0 = (long)blockIdx.x * 64;
#pragma unroll
    for (int it = 0; it < 4; ++it) {
        const int idx = it * 256 + tid;
        const int tk = idx >> 4, c8 = (idx & 15) * 8;
        *(bf16x8*)&t_og[tk * OGP + c8] = *(const bf16x8*)(og + (tok0 + tk) * NC + c8);
    }
    __syncthreads();

    const int w = tid >> 6, L = tid & 63, lh = L >> 5, lc = L & 31;
    f32x16 acc[2];
    acc[0] = fzero16(); acc[1] = fzero16();
#pragma unroll
    for (int k0 = 0; k0 < 8; ++k0) {
        bf16x8 a0 = *(const bf16x8*)&t_og[(lc)      * OGP + k0 * 16 + lh * 8];
        bf16x8 a1 = *(const bf16x8*)&t_og[(32 + lc) * OGP + k0 * 16 + lh * 8];
        bf16x8 b  = *(const bf16x8*)&Wto[(w * 32 + lc) * 128 + k0 * 16 + lh * 8];
        acc[0] = mfma16(a0, b, acc[0]);
        acc[1] = mfma16(a1, b, acc[1]);
    }
    const float bov = bo[w * 32 + lc];
#pragma unroll
    for (int mt = 0; mt < 2; ++mt)
#pragma unroll
        for (int r = 0; r < 16; ++r) {
            const int row = mt * 32 + (r & 3) + 8 * (r >> 2) + 4 * lh;
            out[(tok0 + row) * NC + w * 32 + lc] = acc[mt][r] + bov;
        }
}

// ---------------------------------------------------------------------------
extern "C" void kernel_launch(void* const* d_in, const int* in_sizes, int n_in,
                              void* d_out, int out_size, void* d_ws, size_t ws_size,
                              hipStream_t stream) {
    const float* x     = (const float*)d_in[0];
    const float* mask  = (const float*)d_in[1];
    const float* ln_w  = (const float*)d_in[3];
    const float* ln_b  = (const float*)d_in[4];
    const float* w_tri = (const float*)d_in[5];
    const float* wq    = (const float*)d_in[6];
    const float* wk    = (const float*)d_in[7];
    const float* wv    = (const float*)d_in[8];
    const float* wg    = (const float*)d_in[9];
    const float* bg    = (const float*)d_in[10];
    const float* wo    = (const float*)d_in[11];
    const float* bo    = (const float*)d_in[12];
    float* out = (float*)d_out;

    char* p = (char*)d_ws;
    const long TOK = (long)NI * NJ;                     // 65536
    const long QB  = TOK * NC * sizeof(unsigned short); // 16.78 MB
    unsigned short* q  = (unsigned short*)p; p += QB;
    unsigned short* k  = (unsigned short*)p; p += QB;
    unsigned short* v  = (unsigned short*)p; p += QB;
    unsigned short* g  = (unsigned short*)p; p += QB;
    unsigned short* og = (unsigned short*)p; p += QB;
    float* tri = (float*)p; p += (long)NH * NI * NJ * sizeof(float);
    unsigned short* Wt_all   = (unsigned short*)p; p += 4 * 128 * 128 * sizeof(unsigned short);
    unsigned short* Wto      = (unsigned short*)p; p += 128 * 128 * sizeof(unsigned short);
    unsigned short* Wtri_pad = (unsigned short*)p; p += 32 * 128 * sizeof(unsigned short);

    hipLaunchKernelGGL(convert_weights, dim3(336), dim3(256), 0, stream,
                       wq, wk, wv, wg, wo, w_tri, Wt_all, Wto, Wtri_pad);
    hipLaunchKernelGGL(ln_proj_mfma, dim3(TOK / 64), dim3(256), 0, stream,
                       x, ln_w, ln_b, Wt_all, Wtri_pad, bg, q, k, v, g, tri);
    hipLaunchKernelGGL(attn_mfma, dim3(NI, NH, 2), dim3(256), 0, stream,
                       q, k, v, g, tri, mask, og);
    hipLaunchKernelGGL(out_proj_mfma, dim3(TOK / 64), dim3(256), 0, stream,
                       og, Wto, bo, out);
}

// Round 5
// 179.826 us; speedup vs baseline: 1.1622x; 1.1622x over previous
//
#include <hip/hip_runtime.h>
#include <math.h>

// B=1, I=J=256, C=128, H=4, CH=32
#define NI 256
#define NJ 256
#define NC 128
#define NH 4
#define NCH 32

typedef __attribute__((ext_vector_type(8)))  __bf16        bf16x8;
typedef __attribute__((ext_vector_type(8)))  unsigned short u16x8;
typedef __attribute__((ext_vector_type(4)))  unsigned int   u32x4;
typedef __attribute__((ext_vector_type(16))) float         f32x16;

__device__ __forceinline__ unsigned short f2bf(float f) {
    unsigned u = __builtin_bit_cast(unsigned, f);
    u += 0x7fffu + ((u >> 16) & 1u);          // RNE
    return (unsigned short)(u >> 16);
}
__device__ __forceinline__ float bf2f(unsigned short s) {
    return __builtin_bit_cast(float, ((unsigned)s) << 16);
}
__device__ __forceinline__ f32x16 fzero16() {
    f32x16 z;
#pragma unroll
    for (int r = 0; r < 16; ++r) z[r] = 0.f;
    return z;
}
__device__ __forceinline__ f32x16 mfma16(bf16x8 a, bf16x8 b, f32x16 c) {
    return __builtin_amdgcn_mfma_f32_32x32x16_bf16(a, b, c, 0, 0, 0);
}

// ---------------------------------------------------------------------------
// Kernel 0: transpose+convert weights to bf16.
// ---------------------------------------------------------------------------
__global__ __launch_bounds__(256) void convert_weights(
    const float* __restrict__ wq, const float* __restrict__ wk,
    const float* __restrict__ wv, const float* __restrict__ wg,
    const float* __restrict__ wo, const float* __restrict__ w_tri,
    unsigned short* __restrict__ Wt_all, unsigned short* __restrict__ Wto,
    unsigned short* __restrict__ Wtri_pad)
{
    int id = blockIdx.x * 256 + threadIdx.x;          // 0..86015
    if (id < 4 * 16384) {
        int m = id >> 14, r = id & 16383;
        int kk = r >> 7, c = r & 127;
        const float* W = (m == 0) ? wq : (m == 1) ? wk : (m == 2) ? wv : wg;
        Wt_all[(m * 128 + c) * 128 + kk] = f2bf(W[kk * 128 + c]);
    } else if (id < 5 * 16384) {
        int r = id - 4 * 16384;
        int kk = r >> 7, c = r & 127;
        Wto[c * 128 + kk] = f2bf(wo[kk * 128 + c]);
    } else {
        int r = id - 5 * 16384;                        // 0..4095
        int col = r >> 7, kk = r & 127;
        Wtri_pad[col * 128 + kk] = (col < NH) ? f2bf(w_tri[kk * NH + col]) : (unsigned short)0;
    }
}

// ---------------------------------------------------------------------------
// Kernel 1: LayerNorm + MFMA projections (q,k,v,g) + tri bias via MFMA.
// ---------------------------------------------------------------------------
#define XNP 136
__global__ __launch_bounds__(256, 2) void ln_proj_mfma(
    const float* __restrict__ x, const float* __restrict__ ln_w, const float* __restrict__ ln_b,
    const unsigned short* __restrict__ Wt_all, const unsigned short* __restrict__ Wtri_pad,
    const float* __restrict__ bg,
    unsigned short* __restrict__ q, unsigned short* __restrict__ k,
    unsigned short* __restrict__ v, unsigned short* __restrict__ g,
    float* __restrict__ tri)
{
    __shared__ unsigned short xn[64 * XNP];   // ~17.4 KB
    const int tid = threadIdx.x;
    const long tok0 = (long)blockIdx.x * 64;

    const int lane8 = tid & 7;
#pragma unroll
    for (int p = 0; p < 2; ++p) {
        const int t = p * 32 + (tid >> 3);
        const float4* xrow = (const float4*)(x + (tok0 + t) * NC + lane8 * 16);
        float4 xv[4];
        float s = 0.f;
#pragma unroll
        for (int u = 0; u < 4; ++u) {
            xv[u] = xrow[u];
            s += xv[u].x + xv[u].y + xv[u].z + xv[u].w;
        }
#pragma unroll
        for (int off = 4; off; off >>= 1) s += __shfl_down(s, off, 8);
        const float mu = __shfl(s, 0, 8) * (1.f / (float)NC);
        float s2 = 0.f;
#pragma unroll
        for (int u = 0; u < 4; ++u) {
            float dx;
            dx = xv[u].x - mu; s2 += dx * dx;
            dx = xv[u].y - mu; s2 += dx * dx;
            dx = xv[u].z - mu; s2 += dx * dx;
            dx = xv[u].w - mu; s2 += dx * dx;
        }
#pragma unroll
        for (int off = 4; off; off >>= 1) s2 += __shfl_down(s2, off, 8);
        const float rstd = rsqrtf(__shfl(s2, 0, 8) * (1.f / (float)NC) + 1e-5f);
#pragma unroll
        for (int u = 0; u < 4; ++u) {
            const int c = lane8 * 16 + u * 4;
            const float4 lw = *(const float4*)(ln_w + c);
            const float4 lb = *(const float4*)(ln_b + c);
            float o0 = (xv[u].x - mu) * rstd * lw.x + lb.x;
            float o1 = (xv[u].y - mu) * rstd * lw.y + lb.y;
            float o2 = (xv[u].z - mu) * rstd * lw.z + lb.z;
            float o3 = (xv[u].w - mu) * rstd * lw.w + lb.w;
            unsigned p0 = (unsigned)f2bf(o0) | ((unsigned)f2bf(o1) << 16);
            unsigned p1 = (unsigned)f2bf(o2) | ((unsigned)f2bf(o3) << 16);
            *(unsigned*)&xn[t * XNP + c]     = p0;
            *(unsigned*)&xn[t * XNP + c + 2] = p1;
        }
    }
    __syncthreads();

    const int w = tid >> 6, L = tid & 63, lh = L >> 5, lc = L & 31;
    f32x16 acc[2][4], accT[2];
#pragma unroll
    for (int mt = 0; mt < 2; ++mt) {
        accT[mt] = fzero16();
#pragma unroll
        for (int nt = 0; nt < 4; ++nt) acc[mt][nt] = fzero16();
    }

#pragma unroll
    for (int k0 = 0; k0 < 8; ++k0) {
        bf16x8 a0 = *(const bf16x8*)&xn[(lc)      * XNP + k0 * 16 + lh * 8];
        bf16x8 a1 = *(const bf16x8*)&xn[(32 + lc) * XNP + k0 * 16 + lh * 8];
#pragma unroll
        for (int nt = 0; nt < 4; ++nt) {
            const int ntile = w + 4 * nt;
            bf16x8 b = *(const bf16x8*)&Wt_all[(ntile * 32 + lc) * 128 + k0 * 16 + lh * 8];
            acc[0][nt] = mfma16(a0, b, acc[0][nt]);
            acc[1][nt] = mfma16(a1, b, acc[1][nt]);
        }
        bf16x8 bt = *(const bf16x8*)&Wtri_pad[lc * 128 + k0 * 16 + lh * 8];
        accT[0] = mfma16(a0, bt, accT[0]);
        accT[1] = mfma16(a1, bt, accT[1]);
    }

    const int a_row = (int)(tok0 >> 8);
    const int b0    = (int)(tok0 & 255);
    int rowl[16];
#pragma unroll
    for (int r = 0; r < 16; ++r) rowl[r] = (r & 3) + 8 * (r >> 2) + 4 * lh;

    const float bgv = bg[w * 32 + lc];
#pragma unroll
    for (int nt = 0; nt < 4; ++nt) {
        unsigned short* O = (nt == 0) ? q : (nt == 1) ? k : (nt == 2) ? v : g;
        unsigned short* Ob = O + (((long)a_row * NH + w) * NJ + b0) * NCH + lc;
#pragma unroll
        for (int mt = 0; mt < 2; ++mt) {
#pragma unroll
            for (int r = 0; r < 16; ++r) {
                const int row = mt * 32 + rowl[r];
                float val = acc[mt][nt][r];
                if (nt == 0) val *= 0.17677669529663689f;        // CH^-0.5
                if (nt == 3) val = __builtin_amdgcn_rcpf(1.f + __expf(-(val + bgv)));
                Ob[(long)row * NCH] = f2bf(val);
            }
        }
    }
    if (lc < NH) {
        float* tb = tri + ((long)lc * NI + a_row) * NJ + b0;
#pragma unroll
        for (int mt = 0; mt < 2; ++mt)
#pragma unroll
            for (int r = 0; r < 16; ++r)
                tb[mt * 32 + rowl[r]] = accT[mt][r];
    }
}

// ---------------------------------------------------------------------------
// Kernel 1b: swizzle tri into the S^T C-fragment order:
//   tswz[((h*8+qt)*8+kt)*1024 + lane*16 + reg]
//     = tri[h][qt*32 + (lane&31)][kt*32 + (reg&3)+8*(reg>>2)+4*(lane>>5)]
// ---------------------------------------------------------------------------
#define LSP 260
__global__ __launch_bounds__(256) void swizzle_triT(
    const float* __restrict__ tri, float* __restrict__ tswz)
{
    __shared__ float Ls[32 * LSP];            // ~33 KB
    const int h = blockIdx.x, qt = blockIdx.y;
    const int tid = threadIdx.x;
    // stage 32 rows x 256 cols, coalesced
#pragma unroll
    for (int it = 0; it < 8; ++it) {
        const int fi = it * 256 + tid;        // 0..2047 float4s
        const int row = fi >> 6, c4 = fi & 63;
        *(float4*)&Ls[row * LSP + c4 * 4] =
            *(const float4*)(tri + ((long)h * NI + qt * 32 + row) * NJ + c4 * 4);
    }
    __syncthreads();
    // write: thread covers 32 consecutive outputs (2 lanes x 16 regs)
    const int kt = tid >> 5;
    const int lane2 = (tid & 31) * 2;
    float* dst = tswz + (((long)(h * 8 + qt) * 8 + kt) * 64 + lane2) * 16;
#pragma unroll
    for (int sub = 0; sub < 2; ++sub) {
        const int lane = lane2 + sub;
        const int lc = lane & 31, lhh = lane >> 5;
        float vals[16];
#pragma unroll
        for (int r = 0; r < 16; ++r)
            vals[r] = Ls[lc * LSP + kt * 32 + (r & 3) + 8 * (r >> 2) + 4 * lhh];
#pragma unroll
        for (int u = 0; u < 4; ++u)
            *(float4*)(dst + sub * 16 + u * 4) =
                make_float4(vals[4*u], vals[4*u+1], vals[4*u+2], vals[4*u+3]);
    }
}

// ---------------------------------------------------------------------------
// Kernel 2: fused attention + gating + output projection.
// Block = (i, qh): 128 queries, 256 threads (wave w -> q-tile qh*4+w).
// Loops h=0..3 internally; out^T accumulated in registers across heads;
// epilogue stages out tiles through LDS for coalesced float4 stores.
// ---------------------------------------------------------------------------
#define KSP 40    // Ks row stride (shorts)
#define VTP 264   // Vt row stride (shorts)
#define GSP 40    // Gs row stride (shorts)
#define OSP 36    // outs row stride (floats)
__global__ __launch_bounds__(256, 2) void attn_fused(
    const unsigned short* __restrict__ q, const unsigned short* __restrict__ k,
    const unsigned short* __restrict__ v, const unsigned short* __restrict__ g,
    const float* __restrict__ tswz, const float* __restrict__ mask,
    const unsigned short* __restrict__ Wto, const float* __restrict__ bo,
    float* __restrict__ out)
{
    __shared__ char smem[48640];
    unsigned short* Ks = (unsigned short*)smem;              // 256*40*2 = 20480
    unsigned short* Vt = (unsigned short*)(smem + 20480);    // 32*264*2 = 16896
    unsigned short* Gs = (unsigned short*)(smem + 37376);    // 128*40*2 = 10240
    float*       maskb = (float*)(smem + 47616);             // 1024
    float*        outs = (float*)smem;                       // epilogue reuse: 128*36*4

    const int i = blockIdx.x, qh = blockIdx.y;
    const int tid = threadIdx.x;
    const int w = tid >> 6, L = tid & 63, lh = L >> 5, lc = L & 31;
    const int qt = qh * 4 + w;               // q-tile 0..7
    const int qrow = qt * 32 + lc;           // this lane's query

    maskb[tid] = 1.0e9f * (mask[i * NJ + tid] - 1.0f);

    f32x16 outacc[4];
#pragma unroll
    for (int ct = 0; ct < 4; ++ct) outacc[ct] = fzero16();

    for (int h = 0; h < NH; ++h) {
        if (h) __syncthreads();              // previous head's LDS reads done
        const long base = ((long)i * NH + h) * NJ * NCH;

        // ---- stage K (row-major, padded) ----
#pragma unroll
        for (int it = 0; it < 4; ++it) {
            const int idx = it * 256 + tid;
            const int key = idx >> 2, c8 = (idx & 3) * 8;
            *(bf16x8*)&Ks[key * KSP + c8] = *(const bf16x8*)(k + base + key * NCH + c8);
        }
        // ---- stage V transposed: Vt[ch][key] ----
        {
            const int key = tid;
            const u16x8 r0 = *(const u16x8*)(v + base + key * NCH);
            const u16x8 r1 = *(const u16x8*)(v + base + key * NCH + 8);
            const u16x8 r2 = *(const u16x8*)(v + base + key * NCH + 16);
            const u16x8 r3 = *(const u16x8*)(v + base + key * NCH + 24);
#pragma unroll
            for (int u = 0; u < 8; ++u) {
                Vt[(u)      * VTP + key] = r0[u];
                Vt[(u + 8)  * VTP + key] = r1[u];
                Vt[(u + 16) * VTP + key] = r2[u];
                Vt[(u + 24) * VTP + key] = r3[u];
            }
        }
        // ---- stage G rows for this block's 128 queries ----
#pragma unroll
        for (int it = 0; it < 2; ++it) {
            const int idx = it * 256 + tid;
            const int row = idx >> 2, c8 = (idx & 3) * 8;
            *(bf16x8*)&Gs[row * GSP + c8] =
                *(const bf16x8*)(g + base + (qh * 128 + row) * NCH + c8);
        }
        __syncthreads();

        // ---- Q B-frag ----
        const bf16x8 a0 = *(const bf16x8*)(q + base + (long)qrow * NCH + lh * 8);
        const bf16x8 a1 = *(const bf16x8*)(q + base + (long)qrow * NCH + 16 + lh * 8);
        const float* tbase = tswz + ((long)(h * 8 + qt) * 8) * 1024 + (long)L * 16;

        float ls = 0.f;
        f32x16 O = fzero16();

#pragma unroll
        for (int t = 0; t < 8; ++t) {
            // S^T tile: q = lc, keys = t*32 + rowl(reg,lh)
            bf16x8 kb0 = *(const bf16x8*)&Ks[(t * 32 + lc) * KSP + lh * 8];
            bf16x8 kb1 = *(const bf16x8*)&Ks[(t * 32 + lc) * KSP + 16 + lh * 8];
            f32x16 s = fzero16();
            s = mfma16(kb0, a0, s);
            s = mfma16(kb1, a1, s);

            // bias (pre-swizzled, coalesced) + exp + per-lane sum; pack bf16
            unsigned pk[8];
            const float* tv = tbase + (long)t * 1024;
#pragma unroll
            for (int gg = 0; gg < 4; ++gg) {
                const float4 tb = *(const float4*)(tv + gg * 4);
                const float4 mb = *(const float4*)&maskb[t * 32 + gg * 8 + 4 * lh];
                const float p0 = __expf(fminf(s[4 * gg + 0] + tb.x + mb.x, 30.f));
                const float p1 = __expf(fminf(s[4 * gg + 1] + tb.y + mb.y, 30.f));
                const float p2 = __expf(fminf(s[4 * gg + 2] + tb.z + mb.z, 30.f));
                const float p3 = __expf(fminf(s[4 * gg + 3] + tb.w + mb.w, 30.f));
                ls += (p0 + p1) + (p2 + p3);
                pk[2 * gg]     = (unsigned)f2bf(p0) | ((unsigned)f2bf(p1) << 16);
                pk[2 * gg + 1] = (unsigned)f2bf(p2) | ((unsigned)f2bf(p3) << 16);
            }

            // O^T += V^T @ P^T (in-register B-frag via lane^32 exchange)
#pragma unroll
            for (int ss = 0; ss < 2; ++ss) {
                const unsigned give0 = lh ? pk[4 * ss]     : pk[4 * ss + 2];
                const unsigned give1 = lh ? pk[4 * ss + 1] : pk[4 * ss + 3];
                const unsigned t0 = __shfl_xor(give0, 32);
                const unsigned t1 = __shfl_xor(give1, 32);
                u32x4 bw;
                bw[0] = lh ? t0 : pk[4 * ss];
                bw[1] = lh ? t1 : pk[4 * ss + 1];
                bw[2] = lh ? pk[4 * ss + 2] : t0;
                bw[3] = lh ? pk[4 * ss + 3] : t1;
                const bf16x8 pb = __builtin_bit_cast(bf16x8, bw);
                const bf16x8 va = *(const bf16x8*)&Vt[lc * VTP + t * 32 + ss * 16 + lh * 8];
                O = mfma16(va, pb, O);
            }
        }

        // ---- normalize + gate; pack OG^T to bf16 ----
        ls += __shfl_xor(ls, 32);
        const float rl = __builtin_amdgcn_rcpf(ls);
        unsigned pk2[8];
#pragma unroll
        for (int gg = 0; gg < 4; ++gg) {
            const ushort4 gv = *(const ushort4*)&Gs[(w * 32 + lc) * GSP + gg * 8 + 4 * lh];
            const float o0 = O[4 * gg + 0] * rl * bf2f(gv.x);
            const float o1 = O[4 * gg + 1] * rl * bf2f(gv.y);
            const float o2 = O[4 * gg + 2] * rl * bf2f(gv.z);
            const float o3 = O[4 * gg + 3] * rl * bf2f(gv.w);
            pk2[2 * gg]     = (unsigned)f2bf(o0) | ((unsigned)f2bf(o1) << 16);
            pk2[2 * gg + 1] = (unsigned)f2bf(o2) | ((unsigned)f2bf(o3) << 16);
        }

        // ---- out^T += Wo_h^T @ OG_h^T ----
#pragma unroll
        for (int ss = 0; ss < 2; ++ss) {
            const unsigned give0 = lh ? pk2[4 * ss]     : pk2[4 * ss + 2];
            const unsigned give1 = lh ? pk2[4 * ss + 1] : pk2[4 * ss + 3];
            const unsigned t0 = __shfl_xor(give0, 32);
            const unsigned t1 = __shfl_xor(give1, 32);
            u32x4 bw;
            bw[0] = lh ? t0 : pk2[4 * ss];
            bw[1] = lh ? t1 : pk2[4 * ss + 1];
            bw[2] = lh ? pk2[4 * ss + 2] : t0;
            bw[3] = lh ? pk2[4 * ss + 3] : t1;
            const bf16x8 ogb = __builtin_bit_cast(bf16x8, bw);
#pragma unroll
            for (int ct = 0; ct < 4; ++ct) {
                const bf16x8 wa = *(const bf16x8*)&Wto[(ct * 32 + lc) * 128 + h * 32 + ss * 16 + lh * 8];
                outacc[ct] = mfma16(wa, ogb, outacc[ct]);
            }
        }
    }

    // ---- epilogue: per cout-tile, stage through LDS, coalesced stores ----
    int rowl[16];
#pragma unroll
    for (int r = 0; r < 16; ++r) rowl[r] = (r & 3) + 8 * (r >> 2) + 4 * lh;
#pragma unroll
    for (int ct = 0; ct < 4; ++ct) {
        __syncthreads();                      // protect smem reuse / prev tile reads
#pragma unroll
        for (int r = 0; r < 16; ++r)
            outs[(w * 32 + lc) * OSP + rowl[r]] = outacc[ct][r];
        __syncthreads();
#pragma unroll
        for (int it = 0; it < 4; ++it) {
            const int fi = it * 256 + tid;    // 0..1023 float4s
            const int row = fi >> 3, c4 = fi & 7;
            const float4 vv = *(const float4*)&outs[row * OSP + c4 * 4];
            const float4 bo4 = *(const float4*)(bo + ct * 32 + c4 * 4);
            float4 st;
            st.x = vv.x + bo4.x; st.y = vv.y + bo4.y;
            st.z = vv.z + bo4.z; st.w = vv.w + bo4.w;
            *(float4*)(out + ((long)i * NJ + qh * 128 + row) * NC + ct * 32 + c4 * 4) = st;
        }
    }
}

// ---------------------------------------------------------------------------
extern "C" void kernel_launch(void* const* d_in, const int* in_sizes, int n_in,
                              void* d_out, int out_size, void* d_ws, size_t ws_size,
                              hipStream_t stream) {
    const float* x     = (const float*)d_in[0];
    const float* mask  = (const float*)d_in[1];
    const float* ln_w  = (const float*)d_in[3];
    const float* ln_b  = (const float*)d_in[4];
    const float* w_tri = (const float*)d_in[5];
    const float* wq    = (const float*)d_in[6];
    const float* wk    = (const float*)d_in[7];
    const float* wv    = (const float*)d_in[8];
    const float* wg    = (const float*)d_in[9];
    const float* bg    = (const float*)d_in[10];
    const float* wo    = (const float*)d_in[11];
    const float* bo    = (const float*)d_in[12];
    float* out = (float*)d_out;

    char* p = (char*)d_ws;
    const long TOK = (long)NI * NJ;                     // 65536
    const long QB  = TOK * NC * sizeof(unsigned short); // 16.78 MB
    unsigned short* q  = (unsigned short*)p; p += QB;
    unsigned short* k  = (unsigned short*)p; p += QB;
    unsigned short* v  = (unsigned short*)p; p += QB;
    unsigned short* g  = (unsigned short*)p; p += QB;
    float* tri  = (float*)p; p += (long)NH * NI * NJ * sizeof(float);
    float* tswz = (float*)p; p += (long)NH * NI * NJ * sizeof(float);
    unsigned short* Wt_all   = (unsigned short*)p; p += 4 * 128 * 128 * sizeof(unsigned short);
    unsigned short* Wto      = (unsigned short*)p; p += 128 * 128 * sizeof(unsigned short);
    unsigned short* Wtri_pad = (unsigned short*)p; p += 32 * 128 * sizeof(unsigned short);

    hipLaunchKernelGGL(convert_weights, dim3(336), dim3(256), 0, stream,
                       wq, wk, wv, wg, wo, w_tri, Wt_all, Wto, Wtri_pad);
    hipLaunchKernelGGL(ln_proj_mfma, dim3(TOK / 64), dim3(256), 0, stream,
                       x, ln_w, ln_b, Wt_all, Wtri_pad, bg, q, k, v, g, tri);
    hipLaunchKernelGGL(swizzle_triT, dim3(NH, 8), dim3(256), 0, stream, tri, tswz);
    hipLaunchKernelGGL(attn_fused, dim3(NI, 2), dim3(256), 0, stream,
                       q, k, v, g, tswz, mask, Wto, bo, out);
}